// Round 1
// baseline (314.583 us; speedup 1.0000x reference)
//
#include <hip/hip_runtime.h>
#include <hip/hip_bf16.h>

#define N_EMBD 1024
#define T_SEQ  2048
#define BATCH  2
#define NHEAD  16
#define DKH    64
#define MTOK   (BATCH * T_SEQ)   // 4096

typedef __attribute__((ext_vector_type(8))) short short8;   // 8 x bf16
typedef __attribute__((ext_vector_type(4))) float floatx4;  // MFMA C/D

static __device__ __forceinline__ short bf16_of(float f) {
    union { float f; unsigned u; } x; x.f = f;
    unsigned r = (x.u + 0x7fff + ((x.u >> 16) & 1)) >> 16;
    return (short)r;
}

static __device__ __forceinline__ void async_copy16(const void* g, void* l) {
    __builtin_amdgcn_global_load_lds(
        (const __attribute__((address_space(1))) void*)g,
        (__attribute__((address_space(3))) void*)l,
        16, 0, 0);
}

// ---------------- fp32 -> bf16 convert (n % 4 == 0) ----------------
__global__ __launch_bounds__(256) void cvt_f32_bf16(const float* __restrict__ src,
                                                    short* __restrict__ dst, int n) {
    int i = (blockIdx.x * 256 + threadIdx.x) * 4;
    if (i >= n) return;
    float4 v = *(const float4*)(src + i);
    short4 o;
    o.x = bf16_of(v.x); o.y = bf16_of(v.y); o.z = bf16_of(v.z); o.w = bf16_of(v.w);
    *(short4*)(dst + i) = o;
}

// ---------------- GEMM: C[m][n] = sum_k A[m][k] * Bw[n][k] + bias[n] ----------------
// 128x128 tile, BK=32, 256 threads (4 waves, 2x2 of 64x64), K multiple of 32.
// MODE 0: QKV epilogue (scatter to Q [BH,T,64], K [BH,T,64], Vt [BH,64,T], bf16)
// MODE 1: proj epilogue (fp32 out [M,1024])
template<int MODE>
__global__ __launch_bounds__(256) void gemm_bt(
    const short* __restrict__ A, const short* __restrict__ Bw,
    const float* __restrict__ b0, const float* __restrict__ b1, const float* __restrict__ b2,
    short* __restrict__ outQ, short* __restrict__ outK, short* __restrict__ outV,
    float* __restrict__ outP, int K)
{
    __shared__ short As[128 * 32];
    __shared__ short Bs[128 * 32];
    const int tid  = threadIdx.x;
    const int w    = tid >> 6, lane = tid & 63;
    const int quad = lane >> 4, lr = lane & 15;
    const int wm   = (w & 1) * 64, wn = (w >> 1) * 64;
    const long m0  = (long)blockIdx.y * 128, n0 = (long)blockIdx.x * 128;

    floatx4 acc[4][4] = {};

    // staging: seg s covers rows s*16..s*16+15 (row = 32 shorts = 64B, 16 rows/1KB seg)
    const int srow = lane >> 2;          // 0..15
    const int scol = (lane & 3) * 8;     // 0,8,16,24
    const short* gA = A  + (m0 + w * 16 + srow) * (long)K + scol;
    const short* gB = Bw + (n0 + w * 16 + srow) * (long)K + scol;

    for (int kt = 0; kt < K; kt += 32) {
        async_copy16(gA + kt,            As + w * 512);
        async_copy16(gA + kt + 64L * K,  As + (w + 4) * 512);
        async_copy16(gB + kt,            Bs + w * 512);
        async_copy16(gB + kt + 64L * K,  Bs + (w + 4) * 512);
        __syncthreads();

        const short8* As8 = (const short8*)As;
        const short8* Bs8 = (const short8*)Bs;
        short8 af[4], bf[4];
#pragma unroll
        for (int i = 0; i < 4; ++i) af[i] = As8[(wm + i * 16 + lr) * 4 + quad];
#pragma unroll
        for (int j = 0; j < 4; ++j) bf[j] = Bs8[(wn + j * 16 + lr) * 4 + quad];
#pragma unroll
        for (int i = 0; i < 4; ++i)
#pragma unroll
            for (int j = 0; j < 4; ++j)
                acc[i][j] = __builtin_amdgcn_mfma_f32_16x16x32_bf16(af[i], bf[j], acc[i][j], 0, 0, 0);
        __syncthreads();
    }

#pragma unroll
    for (int i = 0; i < 4; ++i) {
#pragma unroll
        for (int j = 0; j < 4; ++j) {
#pragma unroll
            for (int r = 0; r < 4; ++r) {
                long m = m0 + wm + i * 16 + quad * 4 + r;   // token index
                long n = n0 + wn + j * 16 + lr;             // output feature
                float v = acc[i][j][r];
                if (MODE == 0) {
                    int sel = (int)(n >> 10);
                    int nn  = (int)(n & 1023);
                    v += (sel == 0 ? b0[nn] : (sel == 1 ? b1[nn] : b2[nn]));
                    int  h  = nn >> 6, d = nn & 63;
                    long b  = m >> 11, t = m & 2047;
                    long bh = b * NHEAD + h;
                    if (sel == 0)      outQ[(bh * T_SEQ + t) * DKH + d] = bf16_of(v);
                    else if (sel == 1) outK[(bh * T_SEQ + t) * DKH + d] = bf16_of(v);
                    else               outV[(bh * DKH + d) * T_SEQ + t] = bf16_of(v);
                } else {
                    v += b0[(int)n];
                    outP[m * N_EMBD + n] = v;
                }
            }
        }
    }
}

// ---------------- flash attention: 64 q-rows per block, 4 waves x 16 rows ----------------
__global__ __launch_bounds__(256) void attn_kernel(
    const short* __restrict__ Q, const short* __restrict__ Kb,
    const short* __restrict__ Vt, short* __restrict__ Y)
{
    __shared__ short Ks[64 * 64];          // [key][d]
    __shared__ short Vs[64 * 64];          // [d][key]  (V transposed)
    __shared__ short Ps[4 * 16 * 64];      // per-wave P scratch [16 q][64 key]

    const int tid  = threadIdx.x;
    const int w    = tid >> 6, lane = tid & 63;
    const int quad = lane >> 4, lr = lane & 15;
    const int bh   = blockIdx.y;
    const int q0   = blockIdx.x * 64;
    const int qrb  = q0 + w * 16;          // wave's q-row base

    // Q fragments (A-operand): lane holds Q[qrb+lr][ks*32 + quad*8 .. +8]
    const long qoff = ((long)bh * T_SEQ + qrb + lr) * DKH;
    short8 qf0 = *(const short8*)(Q + qoff + quad * 8);
    short8 qf1 = *(const short8*)(Q + qoff + 32 + quad * 8);

    floatx4 o[4] = {};
    float mi[4], li[4];
#pragma unroll
    for (int r = 0; r < 4; ++r) { mi[r] = -INFINITY; li[r] = 0.f; }

    const int nkt   = blockIdx.x + 1;
    const int srow8 = lane >> 3;           // 0..7 (rows per 1KB seg: 128B rows -> 8)
    const int scol8 = (lane & 7) * 8;

    for (int kt = 0; kt < nkt; ++kt) {
        const int k0 = kt * 64;
        // stage K tile [64 key][64 d] (straight copy) and Vt tile [64 d][64 key]
        {
            const short* gk = Kb + ((long)bh * T_SEQ + k0 + w * 8 + srow8) * DKH + scol8;
            async_copy16(gk,              Ks + w * 512);
            async_copy16(gk + 32L * DKH,  Ks + (w + 4) * 512);
            const short* gv = Vt + ((long)bh * DKH + w * 8 + srow8) * T_SEQ + k0 + scol8;
            async_copy16(gv,                Vs + w * 512);
            async_copy16(gv + 32L * T_SEQ,  Vs + (w + 4) * 512);
        }
        __syncthreads();

        // S = Q K^T  (rows=q, cols=key)
        const short8* Ks8 = (const short8*)Ks;
        floatx4 s[4];
#pragma unroll
        for (int j = 0; j < 4; ++j) {
            floatx4 z = 0.f;
            short8 kb0 = Ks8[(j * 16 + lr) * 8 + quad];
            short8 kb1 = Ks8[(j * 16 + lr) * 8 + 4 + quad];
            z = __builtin_amdgcn_mfma_f32_16x16x32_bf16(qf0, kb0, z, 0, 0, 0);
            z = __builtin_amdgcn_mfma_f32_16x16x32_bf16(qf1, kb1, z, 0, 0, 0);
            s[j] = z;
        }

        const bool diag = (kt == nkt - 1);
        float mnew[4];
#pragma unroll
        for (int r = 0; r < 4; ++r) {
            int qrow = qrb + quad * 4 + r;
            float mx = mi[r];
#pragma unroll
            for (int j = 0; j < 4; ++j) {
                float v = s[j][r] * 0.125f;
                if (diag && (k0 + j * 16 + lr > qrow)) v = -INFINITY;
                s[j][r] = v;
                mx = fmaxf(mx, v);
            }
            mnew[r] = mx;
        }
#pragma unroll
        for (int off = 1; off < 16; off <<= 1)
#pragma unroll
            for (int r = 0; r < 4; ++r)
                mnew[r] = fmaxf(mnew[r], __shfl_xor(mnew[r], off, 64));

        float alpha[4], rs[4];
#pragma unroll
        for (int r = 0; r < 4; ++r) {
            alpha[r] = __expf(mi[r] - mnew[r]);   // -inf -> 0 on first tile
            mi[r] = mnew[r];
            float sum = 0.f;
#pragma unroll
            for (int j = 0; j < 4; ++j) {
                float p = __expf(s[j][r] - mnew[r]);
                s[j][r] = p;
                sum += p;
            }
            rs[r] = sum;
        }
#pragma unroll
        for (int off = 1; off < 16; off <<= 1)
#pragma unroll
            for (int r = 0; r < 4; ++r)
                rs[r] += __shfl_xor(rs[r], off, 64);
#pragma unroll
        for (int r = 0; r < 4; ++r) li[r] = li[r] * alpha[r] + rs[r];
#pragma unroll
        for (int d = 0; d < 4; ++d)
#pragma unroll
            for (int r = 0; r < 4; ++r) o[d][r] *= alpha[r];

        // P (C-layout) -> LDS -> A-layout fragments
        short* Pw = Ps + w * 1024;
#pragma unroll
        for (int j = 0; j < 4; ++j)
#pragma unroll
            for (int r = 0; r < 4; ++r)
                Pw[(quad * 4 + r) * 64 + j * 16 + lr] = bf16_of(s[j][r]);

        const short8* Ps8 = (const short8*)(Ps + w * 1024);
        const short8* Vs8 = (const short8*)Vs;
        short8 pa0 = Ps8[lr * 8 + quad];
        short8 pa1 = Ps8[lr * 8 + 4 + quad];
#pragma unroll
        for (int d = 0; d < 4; ++d) {
            short8 vb0 = Vs8[(d * 16 + lr) * 8 + quad];
            short8 vb1 = Vs8[(d * 16 + lr) * 8 + 4 + quad];
            o[d] = __builtin_amdgcn_mfma_f32_16x16x32_bf16(pa0, vb0, o[d], 0, 0, 0);
            o[d] = __builtin_amdgcn_mfma_f32_16x16x32_bf16(pa1, vb1, o[d], 0, 0, 0);
        }
        __syncthreads();
    }

    // normalize and write Y as [B, T, H*64] bf16
    const long b = bh >> 4, h = bh & 15;
#pragma unroll
    for (int r = 0; r < 4; ++r) {
        float inv = 1.f / li[r];
        long t = qrb + quad * 4 + r;
#pragma unroll
        for (int d = 0; d < 4; ++d)
            Y[(b * T_SEQ + t) * N_EMBD + h * DKH + d * 16 + lr] = bf16_of(o[d][r] * inv);
    }
}

extern "C" void kernel_launch(void* const* d_in, const int* in_sizes, int n_in,
                              void* d_out, int out_size, void* d_ws, size_t ws_size,
                              hipStream_t stream) {
    const float* x  = (const float*)d_in[0];
    const float* Wq = (const float*)d_in[1];
    const float* bq = (const float*)d_in[2];
    const float* Wk = (const float*)d_in[3];
    const float* bk = (const float*)d_in[4];
    const float* Wv = (const float*)d_in[5];
    const float* bv = (const float*)d_in[6];
    const float* Wo = (const float*)d_in[7];
    const float* bo = (const float*)d_in[8];
    float* out = (float*)d_out;

    char* ws = (char*)d_ws;
    short* xb    = (short*)(ws);                       // [4096,1024] bf16, 8MB; reused as Yb
    short* Wqkvb = (short*)(ws + (8L  << 20));         // [3072,1024] bf16, 6MB
    short* Wob   = (short*)(ws + (14L << 20));         // [1024,1024] bf16, 2MB
    short* Qb    = (short*)(ws + (16L << 20));         // [32,2048,64] bf16, 8MB
    short* Kbuf  = (short*)(ws + (24L << 20));         // [32,2048,64] bf16, 8MB
    short* Vtb   = (short*)(ws + (32L << 20));         // [32,64,2048] bf16, 8MB
    short* Yb    = xb;                                 // reuse (x dead after QKV GEMM)

    cvt_f32_bf16<<<4096, 256, 0, stream>>>(x,  xb, MTOK * N_EMBD);
    cvt_f32_bf16<<<1024, 256, 0, stream>>>(Wq, Wqkvb,               N_EMBD * N_EMBD);
    cvt_f32_bf16<<<1024, 256, 0, stream>>>(Wk, Wqkvb + 1048576,     N_EMBD * N_EMBD);
    cvt_f32_bf16<<<1024, 256, 0, stream>>>(Wv, Wqkvb + 2097152,     N_EMBD * N_EMBD);
    cvt_f32_bf16<<<1024, 256, 0, stream>>>(Wo, Wob,                 N_EMBD * N_EMBD);

    gemm_bt<0><<<dim3(24, 32), 256, 0, stream>>>(xb, Wqkvb, bq, bk, bv,
                                                 Qb, Kbuf, Vtb, nullptr, N_EMBD);
    attn_kernel<<<dim3(32, 32), 256, 0, stream>>>(Qb, Kbuf, Vtb, Yb);
    gemm_bt<1><<<dim3(8, 32), 256, 0, stream>>>(Yb, Wob, bo, nullptr, nullptr,
                                                nullptr, nullptr, nullptr, out, N_EMBD);
}

// Round 2
// 247.190 us; speedup vs baseline: 1.2726x; 1.2726x over previous
//
#include <hip/hip_runtime.h>
#include <hip/hip_bf16.h>

#define N_EMBD 1024
#define T_SEQ  2048
#define BATCH  2
#define NHEAD  16
#define DKH    64
#define MTOK   (BATCH * T_SEQ)   // 4096

typedef __attribute__((ext_vector_type(8))) short short8;   // 8 x bf16
typedef __attribute__((ext_vector_type(4))) float floatx4;  // MFMA C/D

static __device__ __forceinline__ short bf16_of(float f) {
    union { float f; unsigned u; } x; x.f = f;
    unsigned r = (x.u + 0x7fff + ((x.u >> 16) & 1)) >> 16;
    return (short)r;
}

static __device__ __forceinline__ void async_copy16(const void* g, void* l) {
    __builtin_amdgcn_global_load_lds(
        (const __attribute__((address_space(1))) void*)g,
        (__attribute__((address_space(3))) void*)l,
        16, 0, 0);
}

// ---------------- fused fp32 -> bf16 convert for all 5 tensors ----------------
// blocks [0,4096): x ; [4096,5120): Wq ; [5120,6144): Wk ; [6144,7168): Wv ; [7168,8192): Wo
__global__ __launch_bounds__(256) void cvt_all(
    const float* __restrict__ x,  const float* __restrict__ Wq,
    const float* __restrict__ Wk, const float* __restrict__ Wv,
    const float* __restrict__ Wo,
    short* __restrict__ xb, short* __restrict__ Wqkvb, short* __restrict__ Wob) {
    int b = blockIdx.x;
    const float* src; short* dst; long base;
    if (b < 4096) { src = x; dst = xb; base = (long)b * 1024; }
    else {
        int r   = (b - 4096) >> 10;
        base    = (long)((b - 4096) & 1023) * 1024;
        if (r == 0)      { src = Wq; dst = Wqkvb;           }
        else if (r == 1) { src = Wk; dst = Wqkvb + 1048576; }
        else if (r == 2) { src = Wv; dst = Wqkvb + 2097152; }
        else             { src = Wo; dst = Wob;             }
    }
    long i = base + threadIdx.x * 4;
    float4 v = *(const float4*)(src + i);
    short4 o;
    o.x = bf16_of(v.x); o.y = bf16_of(v.y); o.z = bf16_of(v.z); o.w = bf16_of(v.w);
    *(short4*)(dst + i) = o;
}

// ---------------- GEMM: C[m][n] = sum_k A[m][k] * Bw[n][k] + bias[n] ----------------
// 128x128 tile, BK=32, 256 threads (4 waves, 2x2 of 64x64), K multiple of 32.
// MODE 0: QKV epilogue (scatter to Q [BH,T,64], K [BH,T,64], Vt [BH,64,T], bf16)
// MODE 1: proj epilogue (fp32 out [M,1024])
template<int MODE>
__global__ __launch_bounds__(256) void gemm_bt(
    const short* __restrict__ A, const short* __restrict__ Bw,
    const float* __restrict__ b0, const float* __restrict__ b1, const float* __restrict__ b2,
    short* __restrict__ outQ, short* __restrict__ outK, short* __restrict__ outV,
    float* __restrict__ outP, int K)
{
    __shared__ short As[128 * 32];
    __shared__ short Bs[128 * 32];
    const int tid  = threadIdx.x;
    const int w    = tid >> 6, lane = tid & 63;
    const int quad = lane >> 4, lr = lane & 15;
    const int wm   = (w & 1) * 64, wn = (w >> 1) * 64;
    const long m0  = (long)blockIdx.y * 128, n0 = (long)blockIdx.x * 128;

    floatx4 acc[4][4] = {};

    const int srow = lane >> 2;          // 0..15
    const int scol = (lane & 3) * 8;     // 0,8,16,24
    const short* gA = A  + (m0 + w * 16 + srow) * (long)K + scol;
    const short* gB = Bw + (n0 + w * 16 + srow) * (long)K + scol;

    for (int kt = 0; kt < K; kt += 32) {
        async_copy16(gA + kt,            As + w * 512);
        async_copy16(gA + kt + 64L * K,  As + (w + 4) * 512);
        async_copy16(gB + kt,            Bs + w * 512);
        async_copy16(gB + kt + 64L * K,  Bs + (w + 4) * 512);
        __syncthreads();

        const short8* As8 = (const short8*)As;
        const short8* Bs8 = (const short8*)Bs;
        short8 af[4], bf[4];
#pragma unroll
        for (int i = 0; i < 4; ++i) af[i] = As8[(wm + i * 16 + lr) * 4 + quad];
#pragma unroll
        for (int j = 0; j < 4; ++j) bf[j] = Bs8[(wn + j * 16 + lr) * 4 + quad];
#pragma unroll
        for (int i = 0; i < 4; ++i)
#pragma unroll
            for (int j = 0; j < 4; ++j)
                acc[i][j] = __builtin_amdgcn_mfma_f32_16x16x32_bf16(af[i], bf[j], acc[i][j], 0, 0, 0);
        __syncthreads();
    }

#pragma unroll
    for (int i = 0; i < 4; ++i) {
#pragma unroll
        for (int j = 0; j < 4; ++j) {
#pragma unroll
            for (int r = 0; r < 4; ++r) {
                long m = m0 + wm + i * 16 + quad * 4 + r;   // token index
                long n = n0 + wn + j * 16 + lr;             // output feature
                float v = acc[i][j][r];
                if (MODE == 0) {
                    int sel = (int)(n >> 10);
                    int nn  = (int)(n & 1023);
                    v += (sel == 0 ? b0[nn] : (sel == 1 ? b1[nn] : b2[nn]));
                    int  h  = nn >> 6, d = nn & 63;
                    long b  = m >> 11, t = m & 2047;
                    long bh = b * NHEAD + h;
                    if (sel == 0)      outQ[(bh * T_SEQ + t) * DKH + d] = bf16_of(v);
                    else if (sel == 1) outK[(bh * T_SEQ + t) * DKH + d] = bf16_of(v);
                    else               outV[(bh * DKH + d) * T_SEQ + t] = bf16_of(v);
                } else {
                    v += b0[(int)n];
                    outP[m * N_EMBD + n] = v;
                }
            }
        }
    }
}

// ---------------- flash attention, balanced + double-buffered ----------------
// Block handles q-tile pair (p, 31-p): exactly 33 stages of 64 keys each.
// Single __syncthreads per stage; next stage's K/V prefetched into the other
// LDS buffer during compute (drained by the NEXT stage's barrier).
__global__ __launch_bounds__(256) void attn_kernel(
    const short* __restrict__ Q, const short* __restrict__ Kb,
    const short* __restrict__ Vt, short* __restrict__ Y)
{
    __shared__ short Ks[2][64 * 64];       // [buf][key][d]
    __shared__ short Vs[2][64 * 64];       // [buf][d][key]
    __shared__ short Ps[4 * 16 * 64];      // per-wave P scratch [16 q][64 key]

    const int tid  = threadIdx.x;
    const int w    = tid >> 6, lane = tid & 63;
    const int quad = lane >> 4, lr = lane & 15;
    const int bh   = blockIdx.y;

    const int srow8 = lane >> 3;           // 0..7
    const int scol8 = (lane & 7) * 8;
    const short* Kbase = Kb + (long)bh * T_SEQ * DKH;
    const short* Vbase = Vt + (long)bh * DKH * T_SEQ;

    auto issue = [&](int k0, int b) {
        const short* gk = Kbase + (long)(k0 + w * 8 + srow8) * DKH + scol8;
        async_copy16(gk,              &Ks[b][w * 512]);
        async_copy16(gk + 32L * DKH,  &Ks[b][(w + 4) * 512]);
        const short* gv = Vbase + (long)(w * 8 + srow8) * T_SEQ + k0 + scol8;
        async_copy16(gv,                &Vs[b][w * 512]);
        async_copy16(gv + 32L * T_SEQ,  &Vs[b][(w + 4) * 512]);
    };

    const int tiles[2] = { (int)blockIdx.x, 31 - (int)blockIdx.x };
    int buf = 0;
    issue(0, 0);

    const long b_out = bh >> 4, h_out = bh & 15;

    for (int ph = 0; ph < 2; ++ph) {
        const int qt  = tiles[ph];
        const int q0  = qt * 64;
        const int qrb = q0 + w * 16;

        const long qoff = ((long)bh * T_SEQ + qrb + lr) * DKH;
        short8 qf0 = *(const short8*)(Q + qoff + quad * 8);
        short8 qf1 = *(const short8*)(Q + qoff + 32 + quad * 8);

        floatx4 o[4] = {};
        float mi[4], li[4];
#pragma unroll
        for (int r = 0; r < 4; ++r) { mi[r] = -INFINITY; li[r] = 0.f; }

        const int nst = qt + 1;
        for (int s = 0; s < nst; ++s) {
            __syncthreads();               // drains this stage's loads; frees buf^1
            if (s + 1 < nst)      issue((s + 1) * 64, buf ^ 1);
            else if (ph == 0)     issue(0, buf ^ 1);   // cross-phase prefetch

            const int k0 = s * 64;
            const short8* Ks8 = (const short8*)Ks[buf];
            floatx4 sc[4];
#pragma unroll
            for (int j = 0; j < 4; ++j) {
                floatx4 z = 0.f;
                short8 kb0 = Ks8[(j * 16 + lr) * 8 + quad];
                short8 kb1 = Ks8[(j * 16 + lr) * 8 + 4 + quad];
                z = __builtin_amdgcn_mfma_f32_16x16x32_bf16(qf0, kb0, z, 0, 0, 0);
                z = __builtin_amdgcn_mfma_f32_16x16x32_bf16(qf1, kb1, z, 0, 0, 0);
                sc[j] = z;
            }

            const bool diag = (s == nst - 1);
            float mnew[4];
#pragma unroll
            for (int r = 0; r < 4; ++r) {
                int qrow = qrb + quad * 4 + r;
                float mx = mi[r];
#pragma unroll
                for (int j = 0; j < 4; ++j) {
                    float v = sc[j][r] * 0.125f;
                    if (diag && (k0 + j * 16 + lr > qrow)) v = -INFINITY;
                    sc[j][r] = v;
                    mx = fmaxf(mx, v);
                }
                mnew[r] = mx;
            }
#pragma unroll
            for (int off = 1; off < 16; off <<= 1)
#pragma unroll
                for (int r = 0; r < 4; ++r)
                    mnew[r] = fmaxf(mnew[r], __shfl_xor(mnew[r], off, 64));

            float alpha[4], rs[4];
#pragma unroll
            for (int r = 0; r < 4; ++r) {
                alpha[r] = __expf(mi[r] - mnew[r]);
                mi[r] = mnew[r];
                float sum = 0.f;
#pragma unroll
                for (int j = 0; j < 4; ++j) {
                    float p = __expf(sc[j][r] - mnew[r]);
                    sc[j][r] = p;
                    sum += p;
                }
                rs[r] = sum;
            }
#pragma unroll
            for (int off = 1; off < 16; off <<= 1)
#pragma unroll
                for (int r = 0; r < 4; ++r)
                    rs[r] += __shfl_xor(rs[r], off, 64);
#pragma unroll
            for (int r = 0; r < 4; ++r) li[r] = li[r] * alpha[r] + rs[r];
#pragma unroll
            for (int d = 0; d < 4; ++d)
#pragma unroll
                for (int r = 0; r < 4; ++r) o[d][r] *= alpha[r];

            // P (C-layout) -> per-wave LDS -> A-layout fragments
            short* Pw = Ps + w * 1024;
#pragma unroll
            for (int j = 0; j < 4; ++j)
#pragma unroll
                for (int r = 0; r < 4; ++r)
                    Pw[(quad * 4 + r) * 64 + j * 16 + lr] = bf16_of(sc[j][r]);

            const short8* Ps8 = (const short8*)(Ps + w * 1024);
            const short8* Vs8 = (const short8*)Vs[buf];
            short8 pa0 = Ps8[lr * 8 + quad];
            short8 pa1 = Ps8[lr * 8 + 4 + quad];
#pragma unroll
            for (int d = 0; d < 4; ++d) {
                short8 vb0 = Vs8[(d * 16 + lr) * 8 + quad];
                short8 vb1 = Vs8[(d * 16 + lr) * 8 + 4 + quad];
                o[d] = __builtin_amdgcn_mfma_f32_16x16x32_bf16(pa0, vb0, o[d], 0, 0, 0);
                o[d] = __builtin_amdgcn_mfma_f32_16x16x32_bf16(pa1, vb1, o[d], 0, 0, 0);
            }
            buf ^= 1;
        }

        // epilogue: normalize, write Y as [B, T, H*64] bf16
#pragma unroll
        for (int r = 0; r < 4; ++r) {
            float inv = 1.f / li[r];
            long t = qrb + quad * 4 + r;
#pragma unroll
            for (int d = 0; d < 4; ++d)
                Y[(b_out * T_SEQ + t) * N_EMBD + h_out * DKH + d * 16 + lr] =
                    bf16_of(o[d][r] * inv);
        }
    }
}

extern "C" void kernel_launch(void* const* d_in, const int* in_sizes, int n_in,
                              void* d_out, int out_size, void* d_ws, size_t ws_size,
                              hipStream_t stream) {
    const float* x  = (const float*)d_in[0];
    const float* Wq = (const float*)d_in[1];
    const float* bq = (const float*)d_in[2];
    const float* Wk = (const float*)d_in[3];
    const float* bk = (const float*)d_in[4];
    const float* Wv = (const float*)d_in[5];
    const float* bv = (const float*)d_in[6];
    const float* Wo = (const float*)d_in[7];
    const float* bo = (const float*)d_in[8];
    float* out = (float*)d_out;

    char* ws = (char*)d_ws;
    short* xb    = (short*)(ws);                       // [4096,1024] bf16, 8MB; reused as Yb
    short* Wqkvb = (short*)(ws + (8L  << 20));         // [3072,1024] bf16, 6MB
    short* Wob   = (short*)(ws + (14L << 20));         // [1024,1024] bf16, 2MB
    short* Qb    = (short*)(ws + (16L << 20));         // [32,2048,64] bf16, 8MB
    short* Kbuf  = (short*)(ws + (24L << 20));         // [32,2048,64] bf16, 8MB
    short* Vtb   = (short*)(ws + (32L << 20));         // [32,64,2048] bf16, 8MB
    short* Yb    = xb;                                 // reuse (x dead after QKV GEMM)

    cvt_all<<<8192, 256, 0, stream>>>(x, Wq, Wk, Wv, Wo, xb, Wqkvb, Wob);

    gemm_bt<0><<<dim3(24, 32), 256, 0, stream>>>(xb, Wqkvb, bq, bk, bv,
                                                 Qb, Kbuf, Vtb, nullptr, N_EMBD);
    attn_kernel<<<dim3(16, 32), 256, 0, stream>>>(Qb, Kbuf, Vtb, Yb);
    gemm_bt<1><<<dim3(8, 32), 256, 0, stream>>>(Yb, Wob, bo, nullptr, nullptr,
                                                nullptr, nullptr, nullptr, out, N_EMBD);
}

// Round 3
// 227.316 us; speedup vs baseline: 1.3839x; 1.0874x over previous
//
#include <hip/hip_runtime.h>
#include <hip/hip_bf16.h>

#define N_EMBD 1024
#define T_SEQ  2048
#define BATCH  2
#define NHEAD  16
#define DKH    64
#define MTOK   (BATCH * T_SEQ)   // 4096

typedef __attribute__((ext_vector_type(8))) short short8;   // 8 x bf16
typedef __attribute__((ext_vector_type(4))) float floatx4;  // MFMA C/D

#define QSCALE 0.18033688011112042f   // 0.125 * log2(e), folded into Q

static __device__ __forceinline__ short bf16_of(float f) {
    union { float f; unsigned u; } x; x.f = f;
    unsigned r = (x.u + 0x7fff + ((x.u >> 16) & 1)) >> 16;
    return (short)r;
}

static __device__ __forceinline__ void async_copy16(const void* g, void* l) {
    __builtin_amdgcn_global_load_lds(
        (const __attribute__((address_space(1))) void*)g,
        (__attribute__((address_space(3))) void*)l,
        16, 0, 0);
}

// ---------------- fused fp32 -> bf16 convert for all 5 tensors ----------------
__global__ __launch_bounds__(256) void cvt_all(
    const float* __restrict__ x,  const float* __restrict__ Wq,
    const float* __restrict__ Wk, const float* __restrict__ Wv,
    const float* __restrict__ Wo,
    short* __restrict__ xb, short* __restrict__ Wqkvb, short* __restrict__ Wob) {
    int b = blockIdx.x;
    const float* src; short* dst; long base;
    if (b < 4096) { src = x; dst = xb; base = (long)b * 1024; }
    else {
        int r   = (b - 4096) >> 10;
        base    = (long)((b - 4096) & 1023) * 1024;
        if (r == 0)      { src = Wq; dst = Wqkvb;           }
        else if (r == 1) { src = Wk; dst = Wqkvb + 1048576; }
        else if (r == 2) { src = Wv; dst = Wqkvb + 2097152; }
        else             { src = Wo; dst = Wob;             }
    }
    long i = base + threadIdx.x * 4;
    float4 v = *(const float4*)(src + i);
    short4 o;
    o.x = bf16_of(v.x); o.y = bf16_of(v.y); o.z = bf16_of(v.z); o.w = bf16_of(v.w);
    *(short4*)(dst + i) = o;
}

// ---------------- GEMM: C[m][n] = sum_k A[m][k] * Bw[n][k] + bias[n] ----------------
// MODE 0: QKV epilogue (Q scaled by QSCALE; scatter Q/K [BH,T,64], Vt [BH,64,T])
// MODE 1: proj epilogue (fp32 out [M,1024])
template<int MODE>
__global__ __launch_bounds__(256) void gemm_bt(
    const short* __restrict__ A, const short* __restrict__ Bw,
    const float* __restrict__ b0, const float* __restrict__ b1, const float* __restrict__ b2,
    short* __restrict__ outQ, short* __restrict__ outK, short* __restrict__ outV,
    float* __restrict__ outP, int K)
{
    __shared__ short As[128 * 32];
    __shared__ short Bs[128 * 32];
    const int tid  = threadIdx.x;
    const int w    = tid >> 6, lane = tid & 63;
    const int quad = lane >> 4, lr = lane & 15;
    const int wm   = (w & 1) * 64, wn = (w >> 1) * 64;
    const long m0  = (long)blockIdx.y * 128, n0 = (long)blockIdx.x * 128;

    floatx4 acc[4][4] = {};

    const int srow = lane >> 2;          // 0..15
    const int scol = (lane & 3) * 8;     // 0,8,16,24
    const short* gA = A  + (m0 + w * 16 + srow) * (long)K + scol;
    const short* gB = Bw + (n0 + w * 16 + srow) * (long)K + scol;

    for (int kt = 0; kt < K; kt += 32) {
        async_copy16(gA + kt,            As + w * 512);
        async_copy16(gA + kt + 64L * K,  As + (w + 4) * 512);
        async_copy16(gB + kt,            Bs + w * 512);
        async_copy16(gB + kt + 64L * K,  Bs + (w + 4) * 512);
        __syncthreads();

        const short8* As8 = (const short8*)As;
        const short8* Bs8 = (const short8*)Bs;
        short8 af[4], bf[4];
#pragma unroll
        for (int i = 0; i < 4; ++i) af[i] = As8[(wm + i * 16 + lr) * 4 + quad];
#pragma unroll
        for (int j = 0; j < 4; ++j) bf[j] = Bs8[(wn + j * 16 + lr) * 4 + quad];
#pragma unroll
        for (int i = 0; i < 4; ++i)
#pragma unroll
            for (int j = 0; j < 4; ++j)
                acc[i][j] = __builtin_amdgcn_mfma_f32_16x16x32_bf16(af[i], bf[j], acc[i][j], 0, 0, 0);
        __syncthreads();
    }

#pragma unroll
    for (int i = 0; i < 4; ++i) {
#pragma unroll
        for (int j = 0; j < 4; ++j) {
#pragma unroll
            for (int r = 0; r < 4; ++r) {
                long m = m0 + wm + i * 16 + quad * 4 + r;   // token index
                long n = n0 + wn + j * 16 + lr;             // output feature
                float v = acc[i][j][r];
                if (MODE == 0) {
                    int sel = (int)(n >> 10);
                    int nn  = (int)(n & 1023);
                    v += (sel == 0 ? b0[nn] : (sel == 1 ? b1[nn] : b2[nn]));
                    int  h  = nn >> 6, d = nn & 63;
                    long b  = m >> 11, t = m & 2047;
                    long bh = b * NHEAD + h;
                    if (sel == 0)      outQ[(bh * T_SEQ + t) * DKH + d] = bf16_of(v * QSCALE);
                    else if (sel == 1) outK[(bh * T_SEQ + t) * DKH + d] = bf16_of(v);
                    else               outV[(bh * DKH + d) * T_SEQ + t] = bf16_of(v);
                } else {
                    v += b0[(int)n];
                    outP[m * N_EMBD + n] = v;
                }
            }
        }
    }
}

// ---------------- flash attention: barrier-free stages, global-direct K/V ----------------
// Block = (pair, bh), 4 waves = 2 key-halves x 2 q-subtiles (32 rows each).
// Sequential phases over tiles {p, 31-p} (33 stages/wave, uniform).
// Fixed-max softmax (Q pre-scaled by 0.125*log2e): P = exp2(S), l summed at end.
// LDS: per-wave P scratch (stride 40 shorts = 80 B, conflict-light) + combine bufs.
__global__ __launch_bounds__(256) void attn_kernel(
    const short* __restrict__ Q, const short* __restrict__ Kb,
    const short* __restrict__ Vt, short* __restrict__ Y)
{
    __shared__ short Ps[4 * 32 * 40];      // per-wave [32 q][40]
    __shared__ float Ob[2][32 * 64];       // half-1 partial O per q-subtile
    __shared__ float Lb[2][32];            // half-1 partial l per q-subtile

    const int tid  = threadIdx.x;
    const int w    = tid >> 6, lane = tid & 63;
    const int quad = lane >> 4, lr = lane & 15;
    const int half = w >> 1, qs = w & 1;

    const int id = blockIdx.x;
    const int bh = (id & 7) + 8 * ((id >> 3) & 3);  // XCD swizzle: same-bh -> same XCD
    const int pr = id >> 5;                          // 0..15

    const short* Kbase = Kb + (long)bh * (T_SEQ * DKH);
    const short* Vbase = Vt + (long)bh * (DKH * T_SEQ);
    const short* Qbase = Q  + (long)bh * (T_SEQ * DKH);
    short* Pw = Ps + w * 1280;

    const long b_out = bh >> 4, h_out = bh & 15;
    const int tiles[2] = { pr, 31 - pr };

    for (int ph = 0; ph < 2; ++ph) {
        const int qt  = tiles[ph];
        const int qrb = qt * 64 + qs * 32;           // wave's 32 q-rows base

        short8 qf[2][2];
#pragma unroll
        for (int m = 0; m < 2; ++m)
#pragma unroll
            for (int c = 0; c < 2; ++c)
                qf[m][c] = *(const short8*)(Qbase + (long)(qrb + m * 16 + lr) * DKH + c * 32 + quad * 8);

        floatx4 o[2][4] = {};
        float rs[2][4] = {};

        const int n32 = 2 * qt + 1 + qs;             // total 32-key stages for these rows
        const int h0  = (n32 + 1) >> 1;
        const int sb  = half ? h0  : 0;
        const int se  = half ? n32 : h0;

        short8 kbn[4];
        if (sb < se) {
            const int k0 = sb * 32;
#pragma unroll
            for (int j = 0; j < 2; ++j)
#pragma unroll
                for (int c = 0; c < 2; ++c)
                    kbn[j * 2 + c] = *(const short8*)(Kbase + (long)(k0 + j * 16 + lr) * DKH + c * 32 + quad * 8);
        }

        for (int s = sb; s < se; ++s) {
            const int k0 = s * 32;
            short8 kbc[4];
#pragma unroll
            for (int i = 0; i < 4; ++i) kbc[i] = kbn[i];
            if (s + 1 < se) {
                const int k1 = (s + 1) * 32;
#pragma unroll
                for (int j = 0; j < 2; ++j)
#pragma unroll
                    for (int c = 0; c < 2; ++c)
                        kbn[j * 2 + c] = *(const short8*)(Kbase + (long)(k1 + j * 16 + lr) * DKH + c * 32 + quad * 8);
            }
            // V fragments for this stage (issued early; consumed after softmax)
            short8 vb[4];
#pragma unroll
            for (int d = 0; d < 4; ++d)
                vb[d] = *(const short8*)(Vbase + (long)(d * 16 + lr) * T_SEQ + k0 + quad * 8);

            floatx4 sc[2][2];
#pragma unroll
            for (int m = 0; m < 2; ++m)
#pragma unroll
                for (int j = 0; j < 2; ++j) {
                    floatx4 z = 0.f;
                    z = __builtin_amdgcn_mfma_f32_16x16x32_bf16(qf[m][0], kbc[j * 2 + 0], z, 0, 0, 0);
                    z = __builtin_amdgcn_mfma_f32_16x16x32_bf16(qf[m][1], kbc[j * 2 + 1], z, 0, 0, 0);
                    sc[m][j] = z;
                }

            if (s == n32 - 1) {                      // wave-uniform diagonal stage
#pragma unroll
                for (int m = 0; m < 2; ++m)
#pragma unroll
                    for (int j = 0; j < 2; ++j)
#pragma unroll
                        for (int r = 0; r < 4; ++r) {
                            int qrow = qrb + m * 16 + quad * 4 + r;
                            int k    = k0 + j * 16 + lr;
                            if (k > qrow) sc[m][j][r] = -INFINITY;
                        }
            }

#pragma unroll
            for (int m = 0; m < 2; ++m)
#pragma unroll
                for (int j = 0; j < 2; ++j)
#pragma unroll
                    for (int r = 0; r < 4; ++r) {
                        float p = exp2f(sc[m][j][r]);
                        sc[m][j][r] = p;
                        rs[m][r] += p;
                    }

            // P (C-layout) -> LDS (stride 40) -> A-layout fragments
#pragma unroll
            for (int m = 0; m < 2; ++m)
#pragma unroll
                for (int j = 0; j < 2; ++j)
#pragma unroll
                    for (int r = 0; r < 4; ++r) {
                        union { float f; unsigned u; } x; x.f = sc[m][j][r];
                        Pw[(m * 16 + quad * 4 + r) * 40 + j * 16 + lr] = (short)((x.u + 0x8000u) >> 16);
                    }

            short8 pa[2];
#pragma unroll
            for (int m = 0; m < 2; ++m)
                pa[m] = *(const short8*)(Pw + (m * 16 + lr) * 40 + quad * 8);

#pragma unroll
            for (int m = 0; m < 2; ++m)
#pragma unroll
                for (int d = 0; d < 4; ++d)
                    o[m][d] = __builtin_amdgcn_mfma_f32_16x16x32_bf16(pa[m], vb[d], o[m][d], 0, 0, 0);
        }

        // reduce l across the 16 lr lanes
#pragma unroll
        for (int off = 1; off < 16; off <<= 1)
#pragma unroll
            for (int m = 0; m < 2; ++m)
#pragma unroll
                for (int r = 0; r < 4; ++r)
                    rs[m][r] += __shfl_xor(rs[m][r], off, 64);

        if (half == 1) {
#pragma unroll
            for (int m = 0; m < 2; ++m)
#pragma unroll
                for (int d = 0; d < 4; ++d)
#pragma unroll
                    for (int r = 0; r < 4; ++r)
                        Ob[qs][(m * 16 + quad * 4 + r) * 64 + d * 16 + lr] = o[m][d][r];
            if (lr == 0) {
#pragma unroll
                for (int m = 0; m < 2; ++m)
#pragma unroll
                    for (int r = 0; r < 4; ++r)
                        Lb[qs][m * 16 + quad * 4 + r] = rs[m][r];
            }
        }
        __syncthreads();
        if (half == 0) {
#pragma unroll
            for (int m = 0; m < 2; ++m)
#pragma unroll
                for (int r = 0; r < 4; ++r) {
                    float l   = rs[m][r] + Lb[qs][m * 16 + quad * 4 + r];
                    float inv = 1.f / l;
                    long  t   = qrb + m * 16 + quad * 4 + r;
#pragma unroll
                    for (int d = 0; d < 4; ++d) {
                        float vtot = o[m][d][r] + Ob[qs][(m * 16 + quad * 4 + r) * 64 + d * 16 + lr];
                        Y[(b_out * T_SEQ + t) * N_EMBD + h_out * DKH + d * 16 + lr] = bf16_of(vtot * inv);
                    }
                }
        }
        __syncthreads();
    }
}

extern "C" void kernel_launch(void* const* d_in, const int* in_sizes, int n_in,
                              void* d_out, int out_size, void* d_ws, size_t ws_size,
                              hipStream_t stream) {
    const float* x  = (const float*)d_in[0];
    const float* Wq = (const float*)d_in[1];
    const float* bq = (const float*)d_in[2];
    const float* Wk = (const float*)d_in[3];
    const float* bk = (const float*)d_in[4];
    const float* Wv = (const float*)d_in[5];
    const float* bv = (const float*)d_in[6];
    const float* Wo = (const float*)d_in[7];
    const float* bo = (const float*)d_in[8];
    float* out = (float*)d_out;

    char* ws = (char*)d_ws;
    short* xb    = (short*)(ws);                       // [4096,1024] bf16, 8MB; reused as Yb
    short* Wqkvb = (short*)(ws + (8L  << 20));         // [3072,1024] bf16, 6MB
    short* Wob   = (short*)(ws + (14L << 20));         // [1024,1024] bf16, 2MB
    short* Qb    = (short*)(ws + (16L << 20));         // [32,2048,64] bf16 (pre-scaled), 8MB
    short* Kbuf  = (short*)(ws + (24L << 20));         // [32,2048,64] bf16, 8MB
    short* Vtb   = (short*)(ws + (32L << 20));         // [32,64,2048] bf16, 8MB
    short* Yb    = xb;                                 // reuse (x dead after QKV GEMM)

    cvt_all<<<8192, 256, 0, stream>>>(x, Wq, Wk, Wv, Wo, xb, Wqkvb, Wob);

    gemm_bt<0><<<dim3(24, 32), 256, 0, stream>>>(xb, Wqkvb, bq, bk, bv,
                                                 Qb, Kbuf, Vtb, nullptr, N_EMBD);
    attn_kernel<<<512, 256, 0, stream>>>(Qb, Kbuf, Vtb, Yb);
    gemm_bt<1><<<dim3(8, 32), 256, 0, stream>>>(Yb, Wob, bo, nullptr, nullptr,
                                                nullptr, nullptr, nullptr, out, N_EMBD);
}